// Round 1
// baseline (75.981 us; speedup 1.0000x reference)
//
#include <hip/hip_runtime.h>
#include <hip/hip_bf16.h>

// out[t][c] = x[t][768+c] + sum_d x[t][(c>>6)*256+d] * Wv[c&63][d]
// t in [0, 65536), c in [0,256). Everything else in the reference is dead code.

#define NTOK (16 * 4096)

typedef short bf16x8 __attribute__((ext_vector_type(8)));
typedef float f32x4 __attribute__((ext_vector_type(4)));

__device__ __forceinline__ short f2bf(float f) {
    __hip_bfloat16 h = __float2bfloat16(f);
    return __builtin_bit_cast(short, h);
}

// LDS layout for Wv as bf16 [64 q][256 d], XOR-swizzled on 16B chunks so the
// B-fragment ds_read_b128 (16 rows x same col-slice) spreads across all banks.
__device__ __forceinline__ int wofs(int q, int d) {
    return (((q << 9) | (d << 1)) ^ ((q & 7) << 4));
}

__global__ __launch_bounds__(256, 2) void mha_vcat_kernel(
    const float* __restrict__ x, const float* __restrict__ Wv,
    float* __restrict__ out)
{
    __shared__ char Wlds[64 * 256 * 2];  // 32 KiB

    const int tid = threadIdx.x;

    // ---- Stage W_v (64x256 f32 -> bf16, swizzled). Coalesced: thread t reads
    // 8 consecutive floats at flat = i*2048 + t*8.
    #pragma unroll
    for (int i = 0; i < 8; ++i) {
        const int flat = i * 2048 + tid * 8;
        const float4 lo = *reinterpret_cast<const float4*>(Wv + flat);
        const float4 hi = *reinterpret_cast<const float4*>(Wv + flat + 4);
        bf16x8 wb;
        wb[0] = f2bf(lo.x); wb[1] = f2bf(lo.y); wb[2] = f2bf(lo.z); wb[3] = f2bf(lo.w);
        wb[4] = f2bf(hi.x); wb[5] = f2bf(hi.y); wb[6] = f2bf(hi.z); wb[7] = f2bf(hi.w);
        *reinterpret_cast<bf16x8*>(Wlds + wofs(flat >> 8, flat & 255)) = wb;
    }
    __syncthreads();

    const int wid  = tid >> 6;
    const int lane = tid & 63;
    const int cl   = lane & 15;   // MFMA col-lane (A row / B col / D col)
    const int g    = lane >> 4;   // lane group (k-slice for A/B, row group for D)

    const long tokBase = (long)blockIdx.x * 64 + wid * 16;
    const float* rowp = x + (tokBase + cl) * 1024;

    // Identity B-fragments: B[k_local][c_local] = 1 iff k_local == c_local (+16).
    // Used to fold the x_last_head residual in as an MFMA (X3 * I).
    bf16x8 diag0, diag1;
    #pragma unroll
    for (int j = 0; j < 8; ++j) {
        diag0[j] = (g * 8 + j == cl)      ? f2bf(1.0f) : (short)0;
        diag1[j] = (g * 8 + j == cl + 16) ? f2bf(1.0f) : (short)0;
    }

    f32x4 acc[4][4];
    #pragma unroll
    for (int h = 0; h < 4; ++h)
        #pragma unroll
        for (int n = 0; n < 4; ++n)
            acc[h][n] = (f32x4){0.f, 0.f, 0.f, 0.f};

    #pragma unroll
    for (int kk = 0; kk < 8; ++kk) {
        // A-fragments: 4 heads, each lane reads 8 consecutive f32 of its token row.
        bf16x8 afr[4];
        #pragma unroll
        for (int h = 0; h < 4; ++h) {
            const float* p = rowp + h * 256 + kk * 32 + g * 8;
            const float4 lo = *reinterpret_cast<const float4*>(p);
            const float4 hi = *reinterpret_cast<const float4*>(p + 4);
            afr[h][0] = f2bf(lo.x); afr[h][1] = f2bf(lo.y);
            afr[h][2] = f2bf(lo.z); afr[h][3] = f2bf(lo.w);
            afr[h][4] = f2bf(hi.x); afr[h][5] = f2bf(hi.y);
            afr[h][6] = f2bf(hi.z); afr[h][7] = f2bf(hi.w);
        }
        // B-fragments: shared across heads, read once per kk.
        bf16x8 bfr[4];
        #pragma unroll
        for (int n = 0; n < 4; ++n)
            bfr[n] = *reinterpret_cast<const bf16x8*>(
                Wlds + wofs(n * 16 + cl, kk * 32 + g * 8));

        #pragma unroll
        for (int h = 0; h < 4; ++h)
            #pragma unroll
            for (int n = 0; n < 4; ++n)
                acc[h][n] = __builtin_amdgcn_mfma_f32_16x16x32_bf16(
                    afr[h], bfr[n], acc[h][n], 0, 0, 0);

        // Residual: out cols [kk*32, kk*32+32) += X3[:, kk*32 .. +32) * I
        const int n0 = 2 * kk, n1 = 2 * kk + 1;
        acc[n0 >> 2][n0 & 3] = __builtin_amdgcn_mfma_f32_16x16x32_bf16(
            afr[3], diag0, acc[n0 >> 2][n0 & 3], 0, 0, 0);
        acc[n1 >> 2][n1 & 3] = __builtin_amdgcn_mfma_f32_16x16x32_bf16(
            afr[3], diag1, acc[n1 >> 2][n1 & 3], 0, 0, 0);
    }

    // D layout: col = lane&15, row = (lane>>4)*4 + j  [m89 verified]
    float* outp = out + tokBase * 256;
    #pragma unroll
    for (int h = 0; h < 4; ++h)
        #pragma unroll
        for (int n = 0; n < 4; ++n)
            #pragma unroll
            for (int j = 0; j < 4; ++j)
                outp[(g * 4 + j) * 256 + h * 64 + n * 16 + cl] = acc[h][n][j];
}

extern "C" void kernel_launch(void* const* d_in, const int* in_sizes, int n_in,
                              void* d_out, int out_size, void* d_ws, size_t ws_size,
                              hipStream_t stream) {
    const float* x  = (const float*)d_in[0];
    const float* Wv = (const float*)d_in[3];  // x, W_q, W_k, W_v
    float* out = (float*)d_out;
    mha_vcat_kernel<<<dim3(NTOK / 64), dim3(256), 0, stream>>>(x, Wv, out);
}